// Round 17
// baseline (148.391 us; speedup 1.0000x reference)
//
#include <hip/hip_runtime.h>

#define NPTS 8192
#define NBATCH 4
#define NTOT (NBATCH * NPTS)     // 32768
#define NN 16
#define RAD2 0.25f
#define EPSF 1e-4f
#define BIGF 1e30f

// ---- grid: cell 0.5 over [-4,4), 16 real cells + ghost ring -> 18^3, x fastest ----
#define GC 16
#define GP 18
#define CBS 6144                  // padded per-batch cell stride (>= 18^3 = 5832)
#define NCELL_TOT (NBATCH * CBS)  // 24576

// ---- search: one wave per TWO consecutive (cell-sorted) points ----
#define STHR 256
#define SWV 4
#define PPW 2
#define SNB (NTOT / (SWV * PPW))  // 4096 blocks
#define HCAP 384                  // >= realized max in-RAD2 hits (~330)

// adaptive radius: r0^3 = C / ncand, C = 2.5*(12/pi)*3.375 = 32.23 (target ~40 hits)
#define LOG2C 5.0103f
#define NCLAMP 257                // ncand <= 257 -> r0 clamped to full radius

// ---- ws layout (bytes) ----
#define WS_COUNTS 0
#define WS_DONE   (WS_COUNTS + NCELL_TOT * 4)          // last-block done counter
#define WS_RANGES (WS_DONE + 16)                       // int2
#define WS_CURSOR (WS_RANGES + NCELL_TOT * 8)
#define WS_SORTED (WS_CURSOR + NCELL_TOT * 4)          // float4 (+64 pad)
#define WS_BSUMS  (WS_SORTED + (NTOT + 64) * 16)
#define WS_NEEDED (WS_BSUMS + SNB * 4)

__device__ __forceinline__ int cellc(float v) {
  return min(max((int)floorf((v + 4.0f) * 2.0f), 0), GC - 1);
}

// refined rsqrt: v_rsq + one Newton step (~1-2 ulp; mean over 512K terms absorbs it)
__device__ __forceinline__ float prsqrt(float x) {
  float r = __builtin_amdgcn_rsqf(x);
  r = r * fmaf(-0.5f * x * r, r, 1.5f);
  return r;
}

#define CE(a, b) { const float lo_ = fminf(a, b); const float hi_ = fmaxf(a, b); a = lo_; b = hi_; }

// ============ build (vectorized: 4 points = 3 float4 loads per thread) ============

__global__ __launch_bounds__(256)
void hist_kernel(const float4* __restrict__ pts4, int* __restrict__ counts) {
  const int t = blockIdx.x * 256 + threadIdx.x;    // NTOT/4 threads
  if (t >= NTOT / 4) return;
  const float4 f0 = pts4[t * 3 + 0];
  const float4 f1 = pts4[t * 3 + 1];
  const float4 f2 = pts4[t * 3 + 2];
  const int b = (t * 4) >> 13;                     // 4 consecutive pts share batch
  const int base = b * CBS;
  atomicAdd(&counts[base + ((cellc(f0.z) + 1) * GP + (cellc(f0.y) + 1)) * GP + (cellc(f0.x) + 1)], 1);
  atomicAdd(&counts[base + ((cellc(f1.y) + 1) * GP + (cellc(f1.x) + 1)) * GP + (cellc(f0.w) + 1)], 1);
  atomicAdd(&counts[base + ((cellc(f2.x) + 1) * GP + (cellc(f1.w) + 1)) * GP + (cellc(f1.z) + 1)], 1);
  atomicAdd(&counts[base + ((cellc(f2.w) + 1) * GP + (cellc(f2.z) + 1)) * GP + (cellc(f2.y) + 1)], 1);
}

// 4 blocks x 1024; thread owns 6 contiguous cells held in regs; 2 barriers total
__global__ __launch_bounds__(1024)
void scan_kernel(const int* __restrict__ counts, int2* __restrict__ ranges,
                 int* __restrict__ cursor) {
  __shared__ int wtot[16];
  __shared__ int woff[16];
  const int b = blockIdx.x;
  const int tid = threadIdx.x;
  const int wid = tid >> 6;
  const int lane = tid & 63;
  const int g0 = b * CBS + tid * 6;

  int v[6];
  int lsum = 0;
#pragma unroll
  for (int k = 0; k < 6; ++k) { v[k] = counts[g0 + k]; lsum += v[k]; }

  int x = lsum;
  for (int off = 1; off < 64; off <<= 1) {
    const int t = __shfl_up(x, off, 64);
    if (lane >= off) x += t;
  }
  if (lane == 63) wtot[wid] = x;
  __syncthreads();
  if (wid == 0 && lane < 16) {
    int s = wtot[lane];
    for (int off = 1; off < 16; off <<= 1) {
      const int t = __shfl_up(s, off, 64);
      if (lane >= off) s += t;
    }
    woff[lane] = s - wtot[lane];
  }
  __syncthreads();

  int run = b * NPTS + woff[wid] + (x - lsum);
#pragma unroll
  for (int k = 0; k < 6; ++k) {
    ranges[g0 + k] = make_int2(run, v[k]);
    cursor[g0 + k] = run;
    run += v[k];
  }
}

__global__ __launch_bounds__(256)
void scatter_kernel(const float4* __restrict__ pts4, int* __restrict__ cursor,
                    float4* __restrict__ sorted) {
  const int t = blockIdx.x * 256 + threadIdx.x;    // NTOT/4 threads
  if (t >= NTOT / 4) return;
  const float4 f0 = pts4[t * 3 + 0];
  const float4 f1 = pts4[t * 3 + 1];
  const float4 f2 = pts4[t * 3 + 2];
  const int b = (t * 4) >> 13;
  const int base = b * CBS;
  float px[4] = { f0.x, f0.w, f1.z, f2.y };
  float py[4] = { f0.y, f1.x, f1.w, f2.z };
  float pz[4] = { f0.z, f1.y, f2.x, f2.w };
#pragma unroll
  for (int k = 0; k < 4; ++k) {
    const int c = base + ((cellc(pz[k]) + 1) * GP + (cellc(py[k]) + 1)) * GP + (cellc(px[k]) + 1);
    const int pos = atomicAdd(&cursor[c], 1);
    sorted[pos] = make_float4(px[k], py[k], pz[k],
                              fmaf(px[k], px[k], fmaf(py[k], py[k], pz[k] * pz[k])));
  }
}

// ============ search helpers (R16-proven forms) ============

__device__ __forceinline__ int scan1(const float4* __restrict__ sorted,
    const int* rs, const int* re, float rr, int selfp,
    float m2x, float m2y, float m2z, float sp, float* __restrict__ hq, int lane) {
  int hcnt = 0;
  const unsigned long long below = (1ull << lane) - 1ull;
#pragma unroll
  for (int m = 0; m < 9; ++m) {
    const int s = rs[m], e = re[m];
    for (int j0 = s; j0 < e; j0 += 64) {
      const int j = j0 + lane;
      float d2 = BIGF;
      if (j < e) {
        const float4 q = sorted[j];
        d2 = fmaf(q.x, m2x, fmaf(q.y, m2y, fmaf(q.z, m2z, q.w + sp)));
      }
      const bool hit = (d2 < rr) && (j != selfp);
      const unsigned long long bal = __ballot(hit);
      if (bal) {
        const int pos = hcnt + (int)__popcll(bal & below);
        if (hit && pos < HCAP) hq[pos] = d2;
        hcnt += (int)__popcll(bal);
      }
    }
  }
  return hcnt;
}

__device__ __forceinline__ void scan2(const float4* __restrict__ sorted,
    const int* rs, const int* re, float rr,
    int pA, float m2xA, float m2yA, float m2zA, float spA,
    int pB, float m2xB, float m2yB, float m2zB, float spB,
    float* __restrict__ hqA, float* __restrict__ hqB, int lane,
    int& hcntA, int& hcntB) {
  int hA = 0, hB = 0;
  const unsigned long long below = (1ull << lane) - 1ull;
#pragma unroll
  for (int m = 0; m < 9; ++m) {
    const int s = rs[m], e = re[m];
    for (int j0 = s; j0 < e; j0 += 64) {
      const int j = j0 + lane;
      float d2A = BIGF, d2B = BIGF;
      if (j < e) {
        const float4 q = sorted[j];
        const float qw = q.w;
        d2A = fmaf(q.x, m2xA, fmaf(q.y, m2yA, fmaf(q.z, m2zA, qw + spA)));
        d2B = fmaf(q.x, m2xB, fmaf(q.y, m2yB, fmaf(q.z, m2zB, qw + spB)));
      }
      const bool hitA = (d2A < rr) && (j != pA);
      const unsigned long long balA = __ballot(hitA);
      if (balA) {
        const int posA = hA + (int)__popcll(balA & below);
        if (hitA && posA < HCAP) hqA[posA] = d2A;
        hA += (int)__popcll(balA);
      }
      const bool hitB = (d2B < rr) && (j != pB);
      const unsigned long long balB = __ballot(hitB);
      if (balB) {
        const int posB = hB + (int)__popcll(balB & below);
        if (hitB && posB < HCAP) hqB[posB] = d2B;
        hB += (int)__popcll(balB);
      }
    }
  }
  hcntA = hA;
  hcntB = hB;
}

template<int R>
__device__ __forceinline__ float tourney(const float* __restrict__ hq, int hn, int lane) {
  float v[R];
#pragma unroll
  for (int r = 0; r < R; ++r) {
    const int idx = lane + 64 * r;
    v[r] = (idx < hn) ? hq[idx] : BIGF;
  }
  if constexpr (R == 3) { CE(v[0], v[1]); CE(v[1], v[2]); CE(v[0], v[1]); }
  if constexpr (R == 6) {
    CE(v[0], v[1]); CE(v[2], v[3]); CE(v[4], v[5]);
    CE(v[1], v[2]); CE(v[3], v[4]);
    CE(v[0], v[1]); CE(v[2], v[3]); CE(v[4], v[5]);
    CE(v[1], v[2]); CE(v[3], v[4]);
    CE(v[0], v[1]); CE(v[2], v[3]); CE(v[4], v[5]);
    CE(v[1], v[2]); CE(v[3], v[4]);
  }
  float loss = 0.0f;
#pragma unroll
  for (int r = 0; r < NN; ++r) {
    float g = v[0];
    g = fminf(g, __shfl_xor(g, 1));
    g = fminf(g, __shfl_xor(g, 2));
    g = fminf(g, __shfl_xor(g, 4));
    g = fminf(g, __shfl_xor(g, 8));
    g = fminf(g, __shfl_xor(g, 16));
    g = fminf(g, __shfl_xor(g, 32));
    loss += prsqrt(g + EPSF);    // hn > 64 here => all 16 mins real, < RAD2
    const unsigned long long own = __ballot(v[0] == g);
    const int first = (int)(__ffsll((unsigned long long)own) - 1);
    if (lane == first) {
#pragma unroll
      for (int r2 = 0; r2 < R - 1; ++r2) v[r2] = v[r2 + 1];
      v[R - 1] = BIGF;
    }
  }
  return loss;
}

__device__ __forceinline__ float extract_loss(const float* __restrict__ hq, int hn, int lane) {
  if (hn <= NN) {
    float l = (lane < hn) ? prsqrt(hq[lane] + EPSF) : 0.0f;
    l += __shfl_xor(l, 1);
    l += __shfl_xor(l, 2);
    l += __shfl_xor(l, 4);
    l += __shfl_xor(l, 8);
    l += __shfl_xor(l, 16);
    l += __shfl_xor(l, 32);
    return l;
  }
  if (hn <= 64) {
    float v = (lane < hn) ? hq[lane] : BIGF;
#pragma unroll
    for (int k = 2; k <= 64; k <<= 1) {
#pragma unroll
      for (int j = k >> 1; j > 0; j >>= 1) {
        const float o = __shfl_xor(v, j, 64);
        const bool keepmin = (((lane & j) == 0) != ((lane & k) != 0));
        v = keepmin ? fminf(v, o) : fmaxf(v, o);
      }
    }
    float l = (lane < NN && v < RAD2) ? prsqrt(v + EPSF) : 0.0f;
    l += __shfl_xor(l, 1);
    l += __shfl_xor(l, 2);
    l += __shfl_xor(l, 4);
    l += __shfl_xor(l, 8);
    l += __shfl_xor(l, 16);
    l += __shfl_xor(l, 32);
    return l;
  } else if (hn <= 192) {
    return tourney<3>(hq, hn, lane);
  }
  return tourney<6>(hq, hn, lane);
}

// ============ search: wave = 2 consecutive cell-sorted points ============
// + fused finalize: each block RELEASE-stores its partial (agent scope), bumps
// a done counter; the unique last block reduces all partials in FIXED order
// (grid-stride + tree) and writes out -> deterministic under any schedule.

__global__ __launch_bounds__(STHR)
void search_kernel(const float4* __restrict__ sorted, const int2* __restrict__ rngs,
                   float* __restrict__ bsums, int* __restrict__ done,
                   float* __restrict__ out) {
  __shared__ float hbuf[SWV][2][HCAP];   // 12.3 KB
  __shared__ float wloss[SWV];
  __shared__ int lastflag;

  const int tid = threadIdx.x;
  const int wv = tid >> 6;
  const int lane = tid & 63;
  const int pair = wv * SNB + blockIdx.x;
  const int p0 = pair * 2;
  const int p1 = p0 + 1;
  const int bb = p0 >> 13;               // pairs never straddle batches (8192 even)

  const float4 ptA = sorted[p0];
  const float4 ptB = sorted[p1];
  const float m2xA = -2.0f * ptA.x, m2yA = -2.0f * ptA.y, m2zA = -2.0f * ptA.z;
  const float spA = ptA.w;
  const float m2xB = -2.0f * ptB.x, m2yB = -2.0f * ptB.y, m2zB = -2.0f * ptB.z;
  const float spB = ptB.w;

  const int rbA = __builtin_amdgcn_readfirstlane(
      bb * CBS + ((cellc(ptA.z) + 1) * GP + (cellc(ptA.y) + 1)) * GP);
  const int rbB = __builtin_amdgcn_readfirstlane(
      bb * CBS + ((cellc(ptB.z) + 1) * GP + (cellc(ptB.y) + 1)) * GP);
  const int xA = __builtin_amdgcn_readfirstlane(cellc(ptA.x));
  const int xB = __builtin_amdgcn_readfirstlane(cellc(ptB.x));

  const int rowoff[9] = {
    (-1 * GP - 1) * GP, (-1 * GP + 0) * GP, (-1 * GP + 1) * GP,
    ( 0 * GP - 1) * GP, ( 0 * GP + 0) * GP, ( 0 * GP + 1) * GP,
    ( 1 * GP - 1) * GP, ( 1 * GP + 0) * GP, ( 1 * GP + 1) * GP };

  float* hqA = hbuf[wv][0];
  float* hqB = hbuf[wv][1];
  int hnA, hnB;

  if (rbA == rbB) {
    // shared/union path (~98% of pairs): same (cy,cz); x-window [min, max+2]
    const int lo = min(xA, xB);
    const int hi = max(xA, xB) + 2;
    int rs[9], re[9], ncand = 0;
#pragma unroll
    for (int m = 0; m < 9; ++m) {
      const int base = rbA + rowoff[m];
      const int2 a = rngs[base + lo];
      const int2 b = rngs[base + hi];
      rs[m] = a.x;
      re[m] = b.x + b.y;
      ncand += re[m] - rs[m];
    }
    const bool clamped = (ncand <= NCLAMP);
    float r0sq = RAD2;
    if (!clamped) r0sq = exp2f((LOG2C - log2f((float)ncand)) * (2.0f / 3.0f));

    int hA, hB;
    scan2(sorted, rs, re, r0sq, p0, m2xA, m2yA, m2zA, spA,
          p1, m2xB, m2yB, m2zB, spB, hqA, hqB, lane, hA, hB);
    hnA = min(hA, HCAP);
    hnB = min(hB, HCAP);
    if (hnA < NN && !clamped)
      hnA = min(scan1(sorted, rs, re, RAD2, p0, m2xA, m2yA, m2zA, spA, hqA, lane), HCAP);
    if (hnB < NN && !clamped)
      hnB = min(scan1(sorted, rs, re, RAD2, p1, m2xB, m2yB, m2zB, spB, hqB, lane), HCAP);
  } else {
    // row-straddle (~1-2%): two independent solo scans
    int rsA[9], reA[9], ncA = 0, rsB[9], reB[9], ncB = 0;
#pragma unroll
    for (int m = 0; m < 9; ++m) {
      const int baseA = rbA + rowoff[m];
      const int2 a0 = rngs[baseA + xA];
      const int2 a1 = rngs[baseA + xA + 2];
      rsA[m] = a0.x; reA[m] = a1.x + a1.y; ncA += reA[m] - rsA[m];
      const int baseB = rbB + rowoff[m];
      const int2 b0 = rngs[baseB + xB];
      const int2 b1 = rngs[baseB + xB + 2];
      rsB[m] = b0.x; reB[m] = b1.x + b1.y; ncB += reB[m] - rsB[m];
    }
    const bool clA = (ncA <= NCLAMP);
    const bool clB = (ncB <= NCLAMP);
    float rA = RAD2, rB = RAD2;
    if (!clA) rA = exp2f((LOG2C - log2f((float)ncA)) * (2.0f / 3.0f));
    if (!clB) rB = exp2f((LOG2C - log2f((float)ncB)) * (2.0f / 3.0f));
    hnA = min(scan1(sorted, rsA, reA, rA, p0, m2xA, m2yA, m2zA, spA, hqA, lane), HCAP);
    if (hnA < NN && !clA)
      hnA = min(scan1(sorted, rsA, reA, RAD2, p0, m2xA, m2yA, m2zA, spA, hqA, lane), HCAP);
    hnB = min(scan1(sorted, rsB, reB, rB, p1, m2xB, m2yB, m2zB, spB, hqB, lane), HCAP);
    if (hnB < NN && !clB)
      hnB = min(scan1(sorted, rsB, reB, RAD2, p1, m2xB, m2yB, m2zB, spB, hqB, lane), HCAP);
  }

  const float lossA = extract_loss(hqA, hnA, lane);
  const float lossB = extract_loss(hqB, hnB, lane);

  if (lane == 0) wloss[wv] = lossA + lossB;
  __syncthreads();
  if (tid == 0) {
    float s = 0.0f;
#pragma unroll
    for (int w = 0; w < SWV; ++w) s += wloss[w];
    // RELEASE store (agent scope): visible across XCD L2s to the last block
    __hip_atomic_store(&bsums[blockIdx.x], s, __ATOMIC_RELEASE, __HIP_MEMORY_SCOPE_AGENT);
    const int d = __hip_atomic_fetch_add(done, 1, __ATOMIC_ACQ_REL, __HIP_MEMORY_SCOPE_AGENT);
    lastflag = (d == SNB - 1);
  }
  __syncthreads();

  // fused finalize: exactly one block runs this; fixed reduction order
  if (lastflag) {
    float v = 0.0f;
    for (int idx = tid; idx < SNB; idx += STHR)
      v += __hip_atomic_load(&bsums[idx], __ATOMIC_RELAXED, __HIP_MEMORY_SCOPE_AGENT);
    __shared__ float s2[STHR];
    s2[tid] = v;
    __syncthreads();
    for (int off = STHR / 2; off > 0; off >>= 1) {
      if (tid < off) s2[tid] += s2[tid + off];
      __syncthreads();
    }
    if (tid == 0) out[0] = s2[0] / (float)(NBATCH * NPTS * NN);
  }
}

__global__ __launch_bounds__(256)
void finalize_kernel(const float* __restrict__ block_sums, int nblocks,
                     float* __restrict__ out) {
  __shared__ float s[256];
  float v = 0.0f;
  for (int idx = threadIdx.x; idx < nblocks; idx += 256) v += block_sums[idx];
  s[threadIdx.x] = v;
  __syncthreads();
  for (int off = 128; off > 0; off >>= 1) {
    if (threadIdx.x < off) s[threadIdx.x] += s[threadIdx.x + off];
    __syncthreads();
  }
  if (threadIdx.x == 0) out[0] = s[0] / (float)(NBATCH * NPTS * NN);
}

// ============ dense fallback (if ws too small) ============

#define DTILE 1024
#define DNT 512
#define DNW 8
#define DNB (NTOT / 64)
#define CSTRIDE 17
#define QTRIG 13

__device__ __forceinline__ void insert16(float (&td)[NN], float& thrmax, float v) {
  if (v < thrmax) {
    bool done = false;
#pragma unroll
    for (int k = 0; k < NN; ++k) {
      const bool hit = (!done) && (td[k] == thrmax);
      if (hit) td[k] = v;
      done = done || hit;
    }
    thrmax = td[0];
#pragma unroll
    for (int k = 1; k < NN; ++k) thrmax = fmaxf(thrmax, td[k]);
  }
}

__device__ __forceinline__ void drain_queue(float* buf, int qbase, int& cnt,
                                            float (&td)[NN], float& thrmax) {
#pragma unroll
  for (int c = 0; c < 16; ++c) {
    const float v = (c < cnt) ? buf[qbase + c] : BIGF;
    insert16(td, thrmax, v);
  }
  cnt = 0;
}

__global__ __launch_bounds__(DNT)
void dense_kernel(const float* __restrict__ pts, float* __restrict__ block_sums) {
  __shared__ float4 tile[DTILE];
  __shared__ float buf[DNT * CSTRIDE];

  const int tid = threadIdx.x;
  const int wave = tid >> 6;
  const int lane = tid & 63;
  const int bid = blockIdx.x;
  const int b = bid / (NPTS / 64);
  const int base = (bid % (NPTS / 64)) * 64;
  const float* __restrict__ bp = pts + (size_t)b * NPTS * 3;

  const int i = base + lane;
  const float xi = bp[i * 3 + 0];
  const float yi = bp[i * 3 + 1];
  const float zi = bp[i * 3 + 2];

  float td[NN];
#pragma unroll
  for (int k = 0; k < NN; ++k) td[k] = BIGF;
  float thrmax = BIGF;
  int cnt = 0;
  const int qbase = tid * CSTRIDE;

  for (int tb = 0; tb < NPTS; tb += DTILE) {
    for (int pp = tid; pp < DTILE; pp += DNT) {
      const float* sp = bp + (size_t)(tb + pp) * 3;
      tile[pp] = make_float4(sp[0], sp[1], sp[2], 0.0f);
    }
    __syncthreads();
    const int jb = wave * (DTILE / DNW);
    for (int jj = 0; jj < DTILE / DNW; ++jj) {
      const float4 q = tile[jb + jj];
      const float ddx = q.x - xi, ddy = q.y - yi, ddz = q.z - zi;
      const float d2 = fmaf(ddx, ddx, fmaf(ddy, ddy, ddz * ddz));
      if (d2 < RAD2 && d2 != 0.0f) {
        buf[qbase + cnt] = d2;
        ++cnt;
      }
      if (__any(cnt >= QTRIG)) drain_queue(buf, qbase, cnt, td, thrmax);
    }
    __syncthreads();
  }
  drain_queue(buf, qbase, cnt, td, thrmax);
#pragma unroll
  for (int k = 0; k < NN; ++k) buf[qbase + k] = td[k];
  __syncthreads();

  if (wave == 0) {
    float sd[NN];
#pragma unroll
    for (int k = 0; k < NN; ++k) sd[k] = BIGF;
    float smax = BIGF;
    for (int w = 0; w < DNW; ++w) {
      for (int c = 0; c < NN; ++c) {
        insert16(sd, smax, buf[(w * 64 + lane) * CSTRIDE + c]);
      }
    }
    float loss = 0.0f;
#pragma unroll
    for (int k = 0; k < NN; ++k) {
      if (sd[k] < RAD2) loss += 1.0f / sqrtf(sd[k] + EPSF);
    }
    for (int off = 32; off > 0; off >>= 1) loss += __shfl_down(loss, off);
    if (lane == 0) block_sums[bid] = loss;
  }
}

// ============ launch ============

extern "C" void kernel_launch(void* const* d_in, const int* in_sizes, int n_in,
                              void* d_out, int out_size, void* d_ws, size_t ws_size,
                              hipStream_t stream) {
  const float* pts = (const float*)d_in[0];
  float* out = (float*)d_out;
  char* ws = (char*)d_ws;

  if (ws_size >= (size_t)WS_NEEDED) {
    int* counts = (int*)(ws + WS_COUNTS);
    int* done = (int*)(ws + WS_DONE);
    int2* rngs = (int2*)(ws + WS_RANGES);
    int* cursor = (int*)(ws + WS_CURSOR);
    float4* sorted = (float4*)(ws + WS_SORTED);
    float* bsums = (float*)(ws + WS_BSUMS);

    hipMemsetAsync(counts, 0, NCELL_TOT * 4 + 16, stream);   // counts + done ctr
    hist_kernel<<<(NTOT / 4 + 255) / 256, 256, 0, stream>>>((const float4*)pts, counts);
    scan_kernel<<<NBATCH, 1024, 0, stream>>>(counts, rngs, cursor);
    scatter_kernel<<<(NTOT / 4 + 255) / 256, 256, 0, stream>>>((const float4*)pts, cursor, sorted);
    search_kernel<<<SNB, STHR, 0, stream>>>(sorted, rngs, bsums, done, out);
  } else {
    float* bsums = (float*)ws;
    dense_kernel<<<DNB, DNT, 0, stream>>>(pts, bsums);
    finalize_kernel<<<1, 256, 0, stream>>>(bsums, DNB, out);
  }
}

// Round 18
// 59.833 us; speedup vs baseline: 2.4801x; 2.4801x over previous
//
#include <hip/hip_runtime.h>

#define NPTS 8192
#define NBATCH 4
#define NTOT (NBATCH * NPTS)     // 32768
#define NN 16
#define RAD2 0.25f
#define EPSF 1e-4f
#define BIGF 1e30f

// ---- grid: cell 0.5 over [-4,4), 16 real cells + ghost ring -> 18^3, x fastest ----
#define GC 16
#define GP 18
#define CBS 6144                  // padded per-batch cell stride (>= 18^3 = 5832)
#define NCELL_TOT (NBATCH * CBS)  // 24576

// ---- search: one wave per TWO consecutive (cell-sorted) points ----
#define STHR 256
#define SWV 4
#define PPW 2
#define SNB (NTOT / (SWV * PPW))  // 4096 blocks
#define HCAP 384                  // >= realized max in-RAD2 hits (~330)

// adaptive radius: r0^3 = C / ncand, C = 2.5*(12/pi)*3.375 = 32.23 (target ~40 hits)
#define LOG2C 5.0103f
#define NCLAMP 257                // ncand <= 257 -> r0 clamped to full radius

// ---- ws layout (bytes) ----
#define WS_COUNTS 0
#define WS_RANGES (WS_COUNTS + NCELL_TOT * 4)          // int2
#define WS_CURSOR (WS_RANGES + NCELL_TOT * 8)
#define WS_SORTED (WS_CURSOR + NCELL_TOT * 4)          // float4 (+64 pad)
#define WS_BSUMS  (WS_SORTED + (NTOT + 64) * 16)
#define WS_NEEDED (WS_BSUMS + SNB * 4)

__device__ __forceinline__ int cellc(float v) {
  return min(max((int)floorf((v + 4.0f) * 2.0f), 0), GC - 1);
}

// refined rsqrt: v_rsq + one Newton step (~1-2 ulp; mean over 512K terms absorbs it)
__device__ __forceinline__ float prsqrt(float x) {
  float r = __builtin_amdgcn_rsqf(x);
  r = r * fmaf(-0.5f * x * r, r, 1.5f);
  return r;
}

#define CE(a, b) { const float lo_ = fminf(a, b); const float hi_ = fmaxf(a, b); a = lo_; b = hi_; }

// ============ build (vectorized: 4 points = 3 float4 loads per thread) ============

__global__ __launch_bounds__(256)
void hist_kernel(const float4* __restrict__ pts4, int* __restrict__ counts) {
  const int t = blockIdx.x * 256 + threadIdx.x;    // NTOT/4 threads
  if (t >= NTOT / 4) return;
  const float4 f0 = pts4[t * 3 + 0];
  const float4 f1 = pts4[t * 3 + 1];
  const float4 f2 = pts4[t * 3 + 2];
  const int b = (t * 4) >> 13;                     // 4 consecutive pts share batch
  const int base = b * CBS;
  atomicAdd(&counts[base + ((cellc(f0.z) + 1) * GP + (cellc(f0.y) + 1)) * GP + (cellc(f0.x) + 1)], 1);
  atomicAdd(&counts[base + ((cellc(f1.y) + 1) * GP + (cellc(f1.x) + 1)) * GP + (cellc(f0.w) + 1)], 1);
  atomicAdd(&counts[base + ((cellc(f2.x) + 1) * GP + (cellc(f1.w) + 1)) * GP + (cellc(f1.z) + 1)], 1);
  atomicAdd(&counts[base + ((cellc(f2.w) + 1) * GP + (cellc(f2.z) + 1)) * GP + (cellc(f2.y) + 1)], 1);
}

// 4 blocks x 1024; thread owns 6 contiguous cells held in regs; 2 barriers total
__global__ __launch_bounds__(1024)
void scan_kernel(const int* __restrict__ counts, int2* __restrict__ ranges,
                 int* __restrict__ cursor) {
  __shared__ int wtot[16];
  __shared__ int woff[16];
  const int b = blockIdx.x;
  const int tid = threadIdx.x;
  const int wid = tid >> 6;
  const int lane = tid & 63;
  const int g0 = b * CBS + tid * 6;

  int v[6];
  int lsum = 0;
#pragma unroll
  for (int k = 0; k < 6; ++k) { v[k] = counts[g0 + k]; lsum += v[k]; }

  int x = lsum;
  for (int off = 1; off < 64; off <<= 1) {
    const int t = __shfl_up(x, off, 64);
    if (lane >= off) x += t;
  }
  if (lane == 63) wtot[wid] = x;
  __syncthreads();
  if (wid == 0 && lane < 16) {
    int s = wtot[lane];
    for (int off = 1; off < 16; off <<= 1) {
      const int t = __shfl_up(s, off, 64);
      if (lane >= off) s += t;
    }
    woff[lane] = s - wtot[lane];
  }
  __syncthreads();

  int run = b * NPTS + woff[wid] + (x - lsum);
#pragma unroll
  for (int k = 0; k < 6; ++k) {
    ranges[g0 + k] = make_int2(run, v[k]);
    cursor[g0 + k] = run;
    run += v[k];
  }
}

__global__ __launch_bounds__(256)
void scatter_kernel(const float4* __restrict__ pts4, int* __restrict__ cursor,
                    float4* __restrict__ sorted) {
  const int t = blockIdx.x * 256 + threadIdx.x;    // NTOT/4 threads
  if (t >= NTOT / 4) return;
  const float4 f0 = pts4[t * 3 + 0];
  const float4 f1 = pts4[t * 3 + 1];
  const float4 f2 = pts4[t * 3 + 2];
  const int b = (t * 4) >> 13;
  const int base = b * CBS;
  float px[4] = { f0.x, f0.w, f1.z, f2.y };
  float py[4] = { f0.y, f1.x, f1.w, f2.z };
  float pz[4] = { f0.z, f1.y, f2.x, f2.w };
#pragma unroll
  for (int k = 0; k < 4; ++k) {
    const int c = base + ((cellc(pz[k]) + 1) * GP + (cellc(py[k]) + 1)) * GP + (cellc(px[k]) + 1);
    const int pos = atomicAdd(&cursor[c], 1);
    sorted[pos] = make_float4(px[k], py[k], pz[k],
                              fmaf(px[k], px[k], fmaf(py[k], py[k], pz[k] * pz[k])));
  }
}

// ============ search helpers (R16-proven forms) ============

__device__ __forceinline__ int scan1(const float4* __restrict__ sorted,
    const int* rs, const int* re, float rr, int selfp,
    float m2x, float m2y, float m2z, float sp, float* __restrict__ hq, int lane) {
  int hcnt = 0;
  const unsigned long long below = (1ull << lane) - 1ull;
#pragma unroll
  for (int m = 0; m < 9; ++m) {
    const int s = rs[m], e = re[m];
    for (int j0 = s; j0 < e; j0 += 64) {
      const int j = j0 + lane;
      float d2 = BIGF;
      if (j < e) {
        const float4 q = sorted[j];
        d2 = fmaf(q.x, m2x, fmaf(q.y, m2y, fmaf(q.z, m2z, q.w + sp)));
      }
      const bool hit = (d2 < rr) && (j != selfp);
      const unsigned long long bal = __ballot(hit);
      if (bal) {
        const int pos = hcnt + (int)__popcll(bal & below);
        if (hit && pos < HCAP) hq[pos] = d2;
        hcnt += (int)__popcll(bal);
      }
    }
  }
  return hcnt;
}

__device__ __forceinline__ void scan2(const float4* __restrict__ sorted,
    const int* rs, const int* re, float rr,
    int pA, float m2xA, float m2yA, float m2zA, float spA,
    int pB, float m2xB, float m2yB, float m2zB, float spB,
    float* __restrict__ hqA, float* __restrict__ hqB, int lane,
    int& hcntA, int& hcntB) {
  int hA = 0, hB = 0;
  const unsigned long long below = (1ull << lane) - 1ull;
#pragma unroll
  for (int m = 0; m < 9; ++m) {
    const int s = rs[m], e = re[m];
    for (int j0 = s; j0 < e; j0 += 64) {
      const int j = j0 + lane;
      float d2A = BIGF, d2B = BIGF;
      if (j < e) {
        const float4 q = sorted[j];
        const float qw = q.w;
        d2A = fmaf(q.x, m2xA, fmaf(q.y, m2yA, fmaf(q.z, m2zA, qw + spA)));
        d2B = fmaf(q.x, m2xB, fmaf(q.y, m2yB, fmaf(q.z, m2zB, qw + spB)));
      }
      const bool hitA = (d2A < rr) && (j != pA);
      const unsigned long long balA = __ballot(hitA);
      if (balA) {
        const int posA = hA + (int)__popcll(balA & below);
        if (hitA && posA < HCAP) hqA[posA] = d2A;
        hA += (int)__popcll(balA);
      }
      const bool hitB = (d2B < rr) && (j != pB);
      const unsigned long long balB = __ballot(hitB);
      if (balB) {
        const int posB = hB + (int)__popcll(balB & below);
        if (hitB && posB < HCAP) hqB[posB] = d2B;
        hB += (int)__popcll(balB);
      }
    }
  }
  hcntA = hA;
  hcntB = hB;
}

template<int R>
__device__ __forceinline__ float tourney(const float* __restrict__ hq, int hn, int lane) {
  float v[R];
#pragma unroll
  for (int r = 0; r < R; ++r) {
    const int idx = lane + 64 * r;
    v[r] = (idx < hn) ? hq[idx] : BIGF;
  }
  if constexpr (R == 3) { CE(v[0], v[1]); CE(v[1], v[2]); CE(v[0], v[1]); }
  if constexpr (R == 6) {
    CE(v[0], v[1]); CE(v[2], v[3]); CE(v[4], v[5]);
    CE(v[1], v[2]); CE(v[3], v[4]);
    CE(v[0], v[1]); CE(v[2], v[3]); CE(v[4], v[5]);
    CE(v[1], v[2]); CE(v[3], v[4]);
    CE(v[0], v[1]); CE(v[2], v[3]); CE(v[4], v[5]);
    CE(v[1], v[2]); CE(v[3], v[4]);
  }
  float loss = 0.0f;
#pragma unroll
  for (int r = 0; r < NN; ++r) {
    float g = v[0];
    g = fminf(g, __shfl_xor(g, 1));
    g = fminf(g, __shfl_xor(g, 2));
    g = fminf(g, __shfl_xor(g, 4));
    g = fminf(g, __shfl_xor(g, 8));
    g = fminf(g, __shfl_xor(g, 16));
    g = fminf(g, __shfl_xor(g, 32));
    loss += prsqrt(g + EPSF);    // hn > 64 here => all 16 mins real, < RAD2
    const unsigned long long own = __ballot(v[0] == g);
    const int first = (int)(__ffsll((unsigned long long)own) - 1);
    if (lane == first) {
#pragma unroll
      for (int r2 = 0; r2 < R - 1; ++r2) v[r2] = v[r2 + 1];
      v[R - 1] = BIGF;
    }
  }
  return loss;
}

__device__ __forceinline__ float extract_loss(const float* __restrict__ hq, int hn, int lane) {
  if (hn <= NN) {
    float l = (lane < hn) ? prsqrt(hq[lane] + EPSF) : 0.0f;
    l += __shfl_xor(l, 1);
    l += __shfl_xor(l, 2);
    l += __shfl_xor(l, 4);
    l += __shfl_xor(l, 8);
    l += __shfl_xor(l, 16);
    l += __shfl_xor(l, 32);
    return l;
  }
  if (hn <= 64) {
    float v = (lane < hn) ? hq[lane] : BIGF;
#pragma unroll
    for (int k = 2; k <= 64; k <<= 1) {
#pragma unroll
      for (int j = k >> 1; j > 0; j >>= 1) {
        const float o = __shfl_xor(v, j, 64);
        const bool keepmin = (((lane & j) == 0) != ((lane & k) != 0));
        v = keepmin ? fminf(v, o) : fmaxf(v, o);
      }
    }
    float l = (lane < NN && v < RAD2) ? prsqrt(v + EPSF) : 0.0f;
    l += __shfl_xor(l, 1);
    l += __shfl_xor(l, 2);
    l += __shfl_xor(l, 4);
    l += __shfl_xor(l, 8);
    l += __shfl_xor(l, 16);
    l += __shfl_xor(l, 32);
    return l;
  } else if (hn <= 192) {
    return tourney<3>(hq, hn, lane);
  }
  return tourney<6>(hq, hn, lane);
}

// ============ search: wave = 2 consecutive cell-sorted points (R16 exact) ============

__global__ __launch_bounds__(STHR)
void search_kernel(const float4* __restrict__ sorted, const int2* __restrict__ rngs,
                   float* __restrict__ bsums) {
  __shared__ float hbuf[SWV][2][HCAP];   // 12.3 KB
  __shared__ float wloss[SWV];

  const int tid = threadIdx.x;
  const int wv = tid >> 6;
  const int lane = tid & 63;
  const int pair = wv * SNB + blockIdx.x;
  const int p0 = pair * 2;
  const int p1 = p0 + 1;
  const int bb = p0 >> 13;               // pairs never straddle batches (8192 even)

  const float4 ptA = sorted[p0];
  const float4 ptB = sorted[p1];
  const float m2xA = -2.0f * ptA.x, m2yA = -2.0f * ptA.y, m2zA = -2.0f * ptA.z;
  const float spA = ptA.w;
  const float m2xB = -2.0f * ptB.x, m2yB = -2.0f * ptB.y, m2zB = -2.0f * ptB.z;
  const float spB = ptB.w;

  const int rbA = __builtin_amdgcn_readfirstlane(
      bb * CBS + ((cellc(ptA.z) + 1) * GP + (cellc(ptA.y) + 1)) * GP);
  const int rbB = __builtin_amdgcn_readfirstlane(
      bb * CBS + ((cellc(ptB.z) + 1) * GP + (cellc(ptB.y) + 1)) * GP);
  const int xA = __builtin_amdgcn_readfirstlane(cellc(ptA.x));
  const int xB = __builtin_amdgcn_readfirstlane(cellc(ptB.x));

  const int rowoff[9] = {
    (-1 * GP - 1) * GP, (-1 * GP + 0) * GP, (-1 * GP + 1) * GP,
    ( 0 * GP - 1) * GP, ( 0 * GP + 0) * GP, ( 0 * GP + 1) * GP,
    ( 1 * GP - 1) * GP, ( 1 * GP + 0) * GP, ( 1 * GP + 1) * GP };

  float* hqA = hbuf[wv][0];
  float* hqB = hbuf[wv][1];
  int hnA, hnB;

  if (rbA == rbB) {
    // shared/union path (~98% of pairs): same (cy,cz); x-window [min, max+2]
    const int lo = min(xA, xB);
    const int hi = max(xA, xB) + 2;
    int rs[9], re[9], ncand = 0;
#pragma unroll
    for (int m = 0; m < 9; ++m) {
      const int base = rbA + rowoff[m];
      const int2 a = rngs[base + lo];
      const int2 b = rngs[base + hi];
      rs[m] = a.x;
      re[m] = b.x + b.y;
      ncand += re[m] - rs[m];
    }
    const bool clamped = (ncand <= NCLAMP);
    float r0sq = RAD2;
    if (!clamped) r0sq = exp2f((LOG2C - log2f((float)ncand)) * (2.0f / 3.0f));

    int hA, hB;
    scan2(sorted, rs, re, r0sq, p0, m2xA, m2yA, m2zA, spA,
          p1, m2xB, m2yB, m2zB, spB, hqA, hqB, lane, hA, hB);
    hnA = min(hA, HCAP);
    hnB = min(hB, HCAP);
    // rare rescans at full radius (union rows are a safe superset for each point)
    if (hnA < NN && !clamped)
      hnA = min(scan1(sorted, rs, re, RAD2, p0, m2xA, m2yA, m2zA, spA, hqA, lane), HCAP);
    if (hnB < NN && !clamped)
      hnB = min(scan1(sorted, rs, re, RAD2, p1, m2xB, m2yB, m2zB, spB, hqB, lane), HCAP);
  } else {
    // row-straddle (~1-2%): two independent solo scans
    int rsA[9], reA[9], ncA = 0, rsB[9], reB[9], ncB = 0;
#pragma unroll
    for (int m = 0; m < 9; ++m) {
      const int baseA = rbA + rowoff[m];
      const int2 a0 = rngs[baseA + xA];
      const int2 a1 = rngs[baseA + xA + 2];
      rsA[m] = a0.x; reA[m] = a1.x + a1.y; ncA += reA[m] - rsA[m];
      const int baseB = rbB + rowoff[m];
      const int2 b0 = rngs[baseB + xB];
      const int2 b1 = rngs[baseB + xB + 2];
      rsB[m] = b0.x; reB[m] = b1.x + b1.y; ncB += reB[m] - rsB[m];
    }
    const bool clA = (ncA <= NCLAMP);
    const bool clB = (ncB <= NCLAMP);
    float rA = RAD2, rB = RAD2;
    if (!clA) rA = exp2f((LOG2C - log2f((float)ncA)) * (2.0f / 3.0f));
    if (!clB) rB = exp2f((LOG2C - log2f((float)ncB)) * (2.0f / 3.0f));
    hnA = min(scan1(sorted, rsA, reA, rA, p0, m2xA, m2yA, m2zA, spA, hqA, lane), HCAP);
    if (hnA < NN && !clA)
      hnA = min(scan1(sorted, rsA, reA, RAD2, p0, m2xA, m2yA, m2zA, spA, hqA, lane), HCAP);
    hnB = min(scan1(sorted, rsB, reB, rB, p1, m2xB, m2yB, m2zB, spB, hqB, lane), HCAP);
    if (hnB < NN && !clB)
      hnB = min(scan1(sorted, rsB, reB, RAD2, p1, m2xB, m2yB, m2zB, spB, hqB, lane), HCAP);
  }

  const float lossA = extract_loss(hqA, hnA, lane);
  const float lossB = extract_loss(hqB, hnB, lane);

  if (lane == 0) wloss[wv] = lossA + lossB;
  __syncthreads();
  if (tid == 0) {
    float s = 0.0f;
#pragma unroll
    for (int w = 0; w < SWV; ++w) s += wloss[w];
    bsums[blockIdx.x] = s;
  }
}

__global__ __launch_bounds__(256)
void finalize_kernel(const float* __restrict__ block_sums, int nblocks,
                     float* __restrict__ out) {
  __shared__ float s[256];
  float v = 0.0f;
  for (int idx = threadIdx.x; idx < nblocks; idx += 256) v += block_sums[idx];
  s[threadIdx.x] = v;
  __syncthreads();
  for (int off = 128; off > 0; off >>= 1) {
    if (threadIdx.x < off) s[threadIdx.x] += s[threadIdx.x + off];
    __syncthreads();
  }
  if (threadIdx.x == 0) out[0] = s[0] / (float)(NBATCH * NPTS * NN);
}

// ============ dense fallback (if ws too small) ============

#define DTILE 1024
#define DNT 512
#define DNW 8
#define DNB (NTOT / 64)
#define CSTRIDE 17
#define QTRIG 13

__device__ __forceinline__ void insert16(float (&td)[NN], float& thrmax, float v) {
  if (v < thrmax) {
    bool done = false;
#pragma unroll
    for (int k = 0; k < NN; ++k) {
      const bool hit = (!done) && (td[k] == thrmax);
      if (hit) td[k] = v;
      done = done || hit;
    }
    thrmax = td[0];
#pragma unroll
    for (int k = 1; k < NN; ++k) thrmax = fmaxf(thrmax, td[k]);
  }
}

__device__ __forceinline__ void drain_queue(float* buf, int qbase, int& cnt,
                                            float (&td)[NN], float& thrmax) {
#pragma unroll
  for (int c = 0; c < 16; ++c) {
    const float v = (c < cnt) ? buf[qbase + c] : BIGF;
    insert16(td, thrmax, v);
  }
  cnt = 0;
}

__global__ __launch_bounds__(DNT)
void dense_kernel(const float* __restrict__ pts, float* __restrict__ block_sums) {
  __shared__ float4 tile[DTILE];
  __shared__ float buf[DNT * CSTRIDE];

  const int tid = threadIdx.x;
  const int wave = tid >> 6;
  const int lane = tid & 63;
  const int bid = blockIdx.x;
  const int b = bid / (NPTS / 64);
  const int base = (bid % (NPTS / 64)) * 64;
  const float* __restrict__ bp = pts + (size_t)b * NPTS * 3;

  const int i = base + lane;
  const float xi = bp[i * 3 + 0];
  const float yi = bp[i * 3 + 1];
  const float zi = bp[i * 3 + 2];

  float td[NN];
#pragma unroll
  for (int k = 0; k < NN; ++k) td[k] = BIGF;
  float thrmax = BIGF;
  int cnt = 0;
  const int qbase = tid * CSTRIDE;

  for (int tb = 0; tb < NPTS; tb += DTILE) {
    for (int pp = tid; pp < DTILE; pp += DNT) {
      const float* sp = bp + (size_t)(tb + pp) * 3;
      tile[pp] = make_float4(sp[0], sp[1], sp[2], 0.0f);
    }
    __syncthreads();
    const int jb = wave * (DTILE / DNW);
    for (int jj = 0; jj < DTILE / DNW; ++jj) {
      const float4 q = tile[jb + jj];
      const float ddx = q.x - xi, ddy = q.y - yi, ddz = q.z - zi;
      const float d2 = fmaf(ddx, ddx, fmaf(ddy, ddy, ddz * ddz));
      if (d2 < RAD2 && d2 != 0.0f) {
        buf[qbase + cnt] = d2;
        ++cnt;
      }
      if (__any(cnt >= QTRIG)) drain_queue(buf, qbase, cnt, td, thrmax);
    }
    __syncthreads();
  }
  drain_queue(buf, qbase, cnt, td, thrmax);
#pragma unroll
  for (int k = 0; k < NN; ++k) buf[qbase + k] = td[k];
  __syncthreads();

  if (wave == 0) {
    float sd[NN];
#pragma unroll
    for (int k = 0; k < NN; ++k) sd[k] = BIGF;
    float smax = BIGF;
    for (int w = 0; w < DNW; ++w) {
      for (int c = 0; c < NN; ++c) {
        insert16(sd, smax, buf[(w * 64 + lane) * CSTRIDE + c]);
      }
    }
    float loss = 0.0f;
#pragma unroll
    for (int k = 0; k < NN; ++k) {
      if (sd[k] < RAD2) loss += 1.0f / sqrtf(sd[k] + EPSF);
    }
    for (int off = 32; off > 0; off >>= 1) loss += __shfl_down(loss, off);
    if (lane == 0) block_sums[bid] = loss;
  }
}

// ============ launch ============

extern "C" void kernel_launch(void* const* d_in, const int* in_sizes, int n_in,
                              void* d_out, int out_size, void* d_ws, size_t ws_size,
                              hipStream_t stream) {
  const float* pts = (const float*)d_in[0];
  float* out = (float*)d_out;
  char* ws = (char*)d_ws;

  if (ws_size >= (size_t)WS_NEEDED) {
    int* counts = (int*)(ws + WS_COUNTS);
    int2* rngs = (int2*)(ws + WS_RANGES);
    int* cursor = (int*)(ws + WS_CURSOR);
    float4* sorted = (float4*)(ws + WS_SORTED);
    float* bsums = (float*)(ws + WS_BSUMS);

    hipMemsetAsync(counts, 0, NCELL_TOT * 4, stream);
    hist_kernel<<<(NTOT / 4 + 255) / 256, 256, 0, stream>>>((const float4*)pts, counts);
    scan_kernel<<<NBATCH, 1024, 0, stream>>>(counts, rngs, cursor);
    scatter_kernel<<<(NTOT / 4 + 255) / 256, 256, 0, stream>>>((const float4*)pts, cursor, sorted);
    search_kernel<<<SNB, STHR, 0, stream>>>(sorted, rngs, bsums);
    finalize_kernel<<<1, 256, 0, stream>>>(bsums, SNB, out);
  } else {
    float* bsums = (float*)ws;
    dense_kernel<<<DNB, DNT, 0, stream>>>(pts, bsums);
    finalize_kernel<<<1, 256, 0, stream>>>(bsums, DNB, out);
  }
}

// Round 19
// 58.832 us; speedup vs baseline: 2.5223x; 1.0170x over previous
//
#include <hip/hip_runtime.h>

#define NPTS 8192
#define NBATCH 4
#define NTOT (NBATCH * NPTS)     // 32768
#define NN 16
#define RAD2 0.25f
#define EPSF 1e-4f
#define BIGF 1e30f

// ---- grid: cell 0.5 over [-4,4), 16 real cells + ghost ring -> 18^3, x fastest ----
#define GC 16
#define GP 18
#define CBS 6144                  // padded per-batch cell stride (>= 18^3 = 5832)
#define NCELL_TOT (NBATCH * CBS)  // 24576

// ---- search: one wave per TWO consecutive (cell-sorted) points ----
#define STHR 256
#define SWV 4
#define PPW 2
#define SNB (NTOT / (SWV * PPW))  // 4096 blocks
#define HCAP 384                  // >= realized max in-RAD2 hits (~330)

// adaptive radius: r0^3 = C / ncand, C = 2.5*(12/pi)*3.375 = 32.23 (target ~40 hits)
#define LOG2C 5.0103f
#define NCLAMP 257                // ncand <= 257 -> r0 clamped to full radius

// ---- ws layout (bytes) ----
#define WS_COUNTS 0
#define WS_RANGES (WS_COUNTS + NCELL_TOT * 4)          // int2
#define WS_CURSOR (WS_RANGES + NCELL_TOT * 8)
#define WS_SORTED (WS_CURSOR + NCELL_TOT * 4)          // float4 (+64 pad)
#define WS_BSUMS  (WS_SORTED + (NTOT + 64) * 16)
#define WS_NEEDED (WS_BSUMS + SNB * 4)

__device__ __forceinline__ int cellc(float v) {
  return min(max((int)floorf((v + 4.0f) * 2.0f), 0), GC - 1);
}

// refined rsqrt: v_rsq + one Newton step (~1-2 ulp; mean over 512K terms absorbs it)
__device__ __forceinline__ float prsqrt(float x) {
  float r = __builtin_amdgcn_rsqf(x);
  r = r * fmaf(-0.5f * x * r, r, 1.5f);
  return r;
}

#define CE(a, b) { const float lo_ = fminf(a, b); const float hi_ = fmaxf(a, b); a = lo_; b = hi_; }

// ============ build (R11-proven) ============

__global__ __launch_bounds__(256)
void hist_kernel(const float* __restrict__ pts, int* __restrict__ counts) {
  const int i = blockIdx.x * 256 + threadIdx.x;
  if (i >= NTOT) return;
  const int b = i >> 13;
  const float x = pts[i * 3 + 0], y = pts[i * 3 + 1], z = pts[i * 3 + 2];
  const int c = b * CBS + ((cellc(z) + 1) * GP + (cellc(y) + 1)) * GP + (cellc(x) + 1);
  atomicAdd(&counts[c], 1);
}

// 4 blocks x 1024; thread owns 6 contiguous cells held in regs; 2 barriers total
__global__ __launch_bounds__(1024)
void scan_kernel(const int* __restrict__ counts, int2* __restrict__ ranges,
                 int* __restrict__ cursor) {
  __shared__ int wtot[16];
  __shared__ int woff[16];
  const int b = blockIdx.x;
  const int tid = threadIdx.x;
  const int wid = tid >> 6;
  const int lane = tid & 63;
  const int g0 = b * CBS + tid * 6;

  int v[6];
  int lsum = 0;
#pragma unroll
  for (int k = 0; k < 6; ++k) { v[k] = counts[g0 + k]; lsum += v[k]; }

  int x = lsum;
  for (int off = 1; off < 64; off <<= 1) {
    const int t = __shfl_up(x, off, 64);
    if (lane >= off) x += t;
  }
  if (lane == 63) wtot[wid] = x;
  __syncthreads();
  if (wid == 0 && lane < 16) {
    int s = wtot[lane];
    for (int off = 1; off < 16; off <<= 1) {
      const int t = __shfl_up(s, off, 64);
      if (lane >= off) s += t;
    }
    woff[lane] = s - wtot[lane];
  }
  __syncthreads();

  int run = b * NPTS + woff[wid] + (x - lsum);
#pragma unroll
  for (int k = 0; k < 6; ++k) {
    ranges[g0 + k] = make_int2(run, v[k]);
    cursor[g0 + k] = run;
    run += v[k];
  }
}

__global__ __launch_bounds__(256)
void scatter_kernel(const float* __restrict__ pts, int* __restrict__ cursor,
                    float4* __restrict__ sorted) {
  const int i = blockIdx.x * 256 + threadIdx.x;
  if (i >= NTOT) return;
  const int b = i >> 13;
  const float x = pts[i * 3 + 0], y = pts[i * 3 + 1], z = pts[i * 3 + 2];
  const int c = b * CBS + ((cellc(z) + 1) * GP + (cellc(y) + 1)) * GP + (cellc(x) + 1);
  const int pos = atomicAdd(&cursor[c], 1);
  sorted[pos] = make_float4(x, y, z, fmaf(x, x, fmaf(y, y, z * z)));
}

// ============ search helpers (R16-proven forms) ============

__device__ __forceinline__ int scan1(const float4* __restrict__ sorted,
    const int* rs, const int* re, float rr, int selfp,
    float m2x, float m2y, float m2z, float sp, float* __restrict__ hq, int lane) {
  int hcnt = 0;
  const unsigned long long below = (1ull << lane) - 1ull;
#pragma unroll
  for (int m = 0; m < 9; ++m) {
    const int s = rs[m], e = re[m];
    for (int j0 = s; j0 < e; j0 += 64) {
      const int j = j0 + lane;
      float d2 = BIGF;
      if (j < e) {
        const float4 q = sorted[j];
        d2 = fmaf(q.x, m2x, fmaf(q.y, m2y, fmaf(q.z, m2z, q.w + sp)));
      }
      const bool hit = (d2 < rr) && (j != selfp);
      const unsigned long long bal = __ballot(hit);
      if (bal) {
        const int pos = hcnt + (int)__popcll(bal & below);
        if (hit && pos < HCAP) hq[pos] = d2;
        hcnt += (int)__popcll(bal);
      }
    }
  }
  return hcnt;
}

__device__ __forceinline__ void scan2(const float4* __restrict__ sorted,
    const int* rs, const int* re, float rr,
    int pA, float m2xA, float m2yA, float m2zA, float spA,
    int pB, float m2xB, float m2yB, float m2zB, float spB,
    float* __restrict__ hqA, float* __restrict__ hqB, int lane,
    int& hcntA, int& hcntB) {
  int hA = 0, hB = 0;
  const unsigned long long below = (1ull << lane) - 1ull;
#pragma unroll
  for (int m = 0; m < 9; ++m) {
    const int s = rs[m], e = re[m];
    for (int j0 = s; j0 < e; j0 += 64) {
      const int j = j0 + lane;
      float d2A = BIGF, d2B = BIGF;
      if (j < e) {
        const float4 q = sorted[j];
        const float qw = q.w;
        d2A = fmaf(q.x, m2xA, fmaf(q.y, m2yA, fmaf(q.z, m2zA, qw + spA)));
        d2B = fmaf(q.x, m2xB, fmaf(q.y, m2yB, fmaf(q.z, m2zB, qw + spB)));
      }
      const bool hitA = (d2A < rr) && (j != pA);
      const unsigned long long balA = __ballot(hitA);
      if (balA) {
        const int posA = hA + (int)__popcll(balA & below);
        if (hitA && posA < HCAP) hqA[posA] = d2A;
        hA += (int)__popcll(balA);
      }
      const bool hitB = (d2B < rr) && (j != pB);
      const unsigned long long balB = __ballot(hitB);
      if (balB) {
        const int posB = hB + (int)__popcll(balB & below);
        if (hitB && posB < HCAP) hqB[posB] = d2B;
        hB += (int)__popcll(balB);
      }
    }
  }
  hcntA = hA;
  hcntB = hB;
}

template<int R>
__device__ __forceinline__ float tourney(const float* __restrict__ hq, int hn, int lane) {
  float v[R];
#pragma unroll
  for (int r = 0; r < R; ++r) {
    const int idx = lane + 64 * r;
    v[r] = (idx < hn) ? hq[idx] : BIGF;
  }
  if constexpr (R == 3) { CE(v[0], v[1]); CE(v[1], v[2]); CE(v[0], v[1]); }
  if constexpr (R == 6) {
    CE(v[0], v[1]); CE(v[2], v[3]); CE(v[4], v[5]);
    CE(v[1], v[2]); CE(v[3], v[4]);
    CE(v[0], v[1]); CE(v[2], v[3]); CE(v[4], v[5]);
    CE(v[1], v[2]); CE(v[3], v[4]);
    CE(v[0], v[1]); CE(v[2], v[3]); CE(v[4], v[5]);
    CE(v[1], v[2]); CE(v[3], v[4]);
  }
  float loss = 0.0f;
#pragma unroll
  for (int r = 0; r < NN; ++r) {
    float g = v[0];
    g = fminf(g, __shfl_xor(g, 1));
    g = fminf(g, __shfl_xor(g, 2));
    g = fminf(g, __shfl_xor(g, 4));
    g = fminf(g, __shfl_xor(g, 8));
    g = fminf(g, __shfl_xor(g, 16));
    g = fminf(g, __shfl_xor(g, 32));
    loss += prsqrt(g + EPSF);    // hn > 64 here => all 16 mins real, < RAD2
    const unsigned long long own = __ballot(v[0] == g);
    const int first = (int)(__ffsll((unsigned long long)own) - 1);
    if (lane == first) {
#pragma unroll
      for (int r2 = 0; r2 < R - 1; ++r2) v[r2] = v[r2 + 1];
      v[R - 1] = BIGF;
    }
  }
  return loss;
}

__device__ __forceinline__ float extract_loss(const float* __restrict__ hq, int hn, int lane) {
  if (hn <= NN) {
    // every hit is among the 16 NN (all < collect radius <= RAD2): direct sum
    float l = (lane < hn) ? prsqrt(hq[lane] + EPSF) : 0.0f;
    l += __shfl_xor(l, 1);
    l += __shfl_xor(l, 2);
    l += __shfl_xor(l, 4);
    l += __shfl_xor(l, 8);
    l += __shfl_xor(l, 16);
    l += __shfl_xor(l, 32);
    return l;
  }
  if (hn <= 64) {
    // bitonic sort 64 across lanes, then sum the 16 smallest
    float v = (lane < hn) ? hq[lane] : BIGF;
#pragma unroll
    for (int k = 2; k <= 64; k <<= 1) {
#pragma unroll
      for (int j = k >> 1; j > 0; j >>= 1) {
        const float o = __shfl_xor(v, j, 64);
        const bool keepmin = (((lane & j) == 0) != ((lane & k) != 0));
        v = keepmin ? fminf(v, o) : fmaxf(v, o);
      }
    }
    float l = (lane < NN && v < RAD2) ? prsqrt(v + EPSF) : 0.0f;
    l += __shfl_xor(l, 1);
    l += __shfl_xor(l, 2);
    l += __shfl_xor(l, 4);
    l += __shfl_xor(l, 8);
    l += __shfl_xor(l, 16);
    l += __shfl_xor(l, 32);
    return l;
  } else if (hn <= 192) {
    return tourney<3>(hq, hn, lane);
  }
  return tourney<6>(hq, hn, lane);
}

// ============ search: wave = 2 consecutive cell-sorted points ============
// Best-measured configuration (R16, 58.8us). Structural floor: per-pair serial
// chain (pt load -> ranges -> first chunk ~600cyc) vs ~600cyc VALU work caps
// VALUBusy at ~55% regardless of occupancy (proven by R15 full-residency test).

__global__ __launch_bounds__(STHR)
void search_kernel(const float4* __restrict__ sorted, const int2* __restrict__ rngs,
                   float* __restrict__ bsums) {
  __shared__ float hbuf[SWV][2][HCAP];   // 12.3 KB
  __shared__ float wloss[SWV];

  const int tid = threadIdx.x;
  const int wv = tid >> 6;
  const int lane = tid & 63;
  const int pair = wv * SNB + blockIdx.x;
  const int p0 = pair * 2;
  const int p1 = p0 + 1;
  const int bb = p0 >> 13;               // pairs never straddle batches (8192 even)

  const float4 ptA = sorted[p0];
  const float4 ptB = sorted[p1];
  const float m2xA = -2.0f * ptA.x, m2yA = -2.0f * ptA.y, m2zA = -2.0f * ptA.z;
  const float spA = ptA.w;
  const float m2xB = -2.0f * ptB.x, m2yB = -2.0f * ptB.y, m2zB = -2.0f * ptB.z;
  const float spB = ptB.w;

  const int rbA = __builtin_amdgcn_readfirstlane(
      bb * CBS + ((cellc(ptA.z) + 1) * GP + (cellc(ptA.y) + 1)) * GP);
  const int rbB = __builtin_amdgcn_readfirstlane(
      bb * CBS + ((cellc(ptB.z) + 1) * GP + (cellc(ptB.y) + 1)) * GP);
  const int xA = __builtin_amdgcn_readfirstlane(cellc(ptA.x));
  const int xB = __builtin_amdgcn_readfirstlane(cellc(ptB.x));

  const int rowoff[9] = {
    (-1 * GP - 1) * GP, (-1 * GP + 0) * GP, (-1 * GP + 1) * GP,
    ( 0 * GP - 1) * GP, ( 0 * GP + 0) * GP, ( 0 * GP + 1) * GP,
    ( 1 * GP - 1) * GP, ( 1 * GP + 0) * GP, ( 1 * GP + 1) * GP };

  float* hqA = hbuf[wv][0];
  float* hqB = hbuf[wv][1];
  int hnA, hnB;

  if (rbA == rbB) {
    // shared/union path (~98% of pairs): same (cy,cz); x-window [min, max+2]
    const int lo = min(xA, xB);
    const int hi = max(xA, xB) + 2;
    int rs[9], re[9], ncand = 0;
#pragma unroll
    for (int m = 0; m < 9; ++m) {
      const int base = rbA + rowoff[m];
      const int2 a = rngs[base + lo];
      const int2 b = rngs[base + hi];
      rs[m] = a.x;
      re[m] = b.x + b.y;
      ncand += re[m] - rs[m];
    }
    const bool clamped = (ncand <= NCLAMP);
    float r0sq = RAD2;
    if (!clamped) r0sq = exp2f((LOG2C - log2f((float)ncand)) * (2.0f / 3.0f));

    int hA, hB;
    scan2(sorted, rs, re, r0sq, p0, m2xA, m2yA, m2zA, spA,
          p1, m2xB, m2yB, m2zB, spB, hqA, hqB, lane, hA, hB);
    hnA = min(hA, HCAP);
    hnB = min(hB, HCAP);
    // rare rescans at full radius (union rows are a safe superset for each point)
    if (hnA < NN && !clamped)
      hnA = min(scan1(sorted, rs, re, RAD2, p0, m2xA, m2yA, m2zA, spA, hqA, lane), HCAP);
    if (hnB < NN && !clamped)
      hnB = min(scan1(sorted, rs, re, RAD2, p1, m2xB, m2yB, m2zB, spB, hqB, lane), HCAP);
  } else {
    // row-straddle (~1-2%): two independent solo scans
    int rsA[9], reA[9], ncA = 0, rsB[9], reB[9], ncB = 0;
#pragma unroll
    for (int m = 0; m < 9; ++m) {
      const int baseA = rbA + rowoff[m];
      const int2 a0 = rngs[baseA + xA];
      const int2 a1 = rngs[baseA + xA + 2];
      rsA[m] = a0.x; reA[m] = a1.x + a1.y; ncA += reA[m] - rsA[m];
      const int baseB = rbB + rowoff[m];
      const int2 b0 = rngs[baseB + xB];
      const int2 b1 = rngs[baseB + xB + 2];
      rsB[m] = b0.x; reB[m] = b1.x + b1.y; ncB += reB[m] - rsB[m];
    }
    const bool clA = (ncA <= NCLAMP);
    const bool clB = (ncB <= NCLAMP);
    float rA = RAD2, rB = RAD2;
    if (!clA) rA = exp2f((LOG2C - log2f((float)ncA)) * (2.0f / 3.0f));
    if (!clB) rB = exp2f((LOG2C - log2f((float)ncB)) * (2.0f / 3.0f));
    hnA = min(scan1(sorted, rsA, reA, rA, p0, m2xA, m2yA, m2zA, spA, hqA, lane), HCAP);
    if (hnA < NN && !clA)
      hnA = min(scan1(sorted, rsA, reA, RAD2, p0, m2xA, m2yA, m2zA, spA, hqA, lane), HCAP);
    hnB = min(scan1(sorted, rsB, reB, rB, p1, m2xB, m2yB, m2zB, spB, hqB, lane), HCAP);
    if (hnB < NN && !clB)
      hnB = min(scan1(sorted, rsB, reB, RAD2, p1, m2xB, m2yB, m2zB, spB, hqB, lane), HCAP);
  }

  const float lossA = extract_loss(hqA, hnA, lane);
  const float lossB = extract_loss(hqB, hnB, lane);

  if (lane == 0) wloss[wv] = lossA + lossB;
  __syncthreads();
  if (tid == 0) {
    float s = 0.0f;
#pragma unroll
    for (int w = 0; w < SWV; ++w) s += wloss[w];
    bsums[blockIdx.x] = s;
  }
}

__global__ __launch_bounds__(256)
void finalize_kernel(const float* __restrict__ block_sums, int nblocks,
                     float* __restrict__ out) {
  __shared__ float s[256];
  float v = 0.0f;
  for (int idx = threadIdx.x; idx < nblocks; idx += 256) v += block_sums[idx];
  s[threadIdx.x] = v;
  __syncthreads();
  for (int off = 128; off > 0; off >>= 1) {
    if (threadIdx.x < off) s[threadIdx.x] += s[threadIdx.x + off];
    __syncthreads();
  }
  if (threadIdx.x == 0) out[0] = s[0] / (float)(NBATCH * NPTS * NN);
}

// ============ dense fallback (if ws too small) ============

#define DTILE 1024
#define DNT 512
#define DNW 8
#define DNB (NTOT / 64)
#define CSTRIDE 17
#define QTRIG 13

__device__ __forceinline__ void insert16(float (&td)[NN], float& thrmax, float v) {
  if (v < thrmax) {
    bool done = false;
#pragma unroll
    for (int k = 0; k < NN; ++k) {
      const bool hit = (!done) && (td[k] == thrmax);
      if (hit) td[k] = v;
      done = done || hit;
    }
    thrmax = td[0];
#pragma unroll
    for (int k = 1; k < NN; ++k) thrmax = fmaxf(thrmax, td[k]);
  }
}

__device__ __forceinline__ void drain_queue(float* buf, int qbase, int& cnt,
                                            float (&td)[NN], float& thrmax) {
#pragma unroll
  for (int c = 0; c < 16; ++c) {
    const float v = (c < cnt) ? buf[qbase + c] : BIGF;
    insert16(td, thrmax, v);
  }
  cnt = 0;
}

__global__ __launch_bounds__(DNT)
void dense_kernel(const float* __restrict__ pts, float* __restrict__ block_sums) {
  __shared__ float4 tile[DTILE];
  __shared__ float buf[DNT * CSTRIDE];

  const int tid = threadIdx.x;
  const int wave = tid >> 6;
  const int lane = tid & 63;
  const int bid = blockIdx.x;
  const int b = bid / (NPTS / 64);
  const int base = (bid % (NPTS / 64)) * 64;
  const float* __restrict__ bp = pts + (size_t)b * NPTS * 3;

  const int i = base + lane;
  const float xi = bp[i * 3 + 0];
  const float yi = bp[i * 3 + 1];
  const float zi = bp[i * 3 + 2];

  float td[NN];
#pragma unroll
  for (int k = 0; k < NN; ++k) td[k] = BIGF;
  float thrmax = BIGF;
  int cnt = 0;
  const int qbase = tid * CSTRIDE;

  for (int tb = 0; tb < NPTS; tb += DTILE) {
    for (int pp = tid; pp < DTILE; pp += DNT) {
      const float* sp = bp + (size_t)(tb + pp) * 3;
      tile[pp] = make_float4(sp[0], sp[1], sp[2], 0.0f);
    }
    __syncthreads();
    const int jb = wave * (DTILE / DNW);
    for (int jj = 0; jj < DTILE / DNW; ++jj) {
      const float4 q = tile[jb + jj];
      const float ddx = q.x - xi, ddy = q.y - yi, ddz = q.z - zi;
      const float d2 = fmaf(ddx, ddx, fmaf(ddy, ddy, ddz * ddz));
      if (d2 < RAD2 && d2 != 0.0f) {
        buf[qbase + cnt] = d2;
        ++cnt;
      }
      if (__any(cnt >= QTRIG)) drain_queue(buf, qbase, cnt, td, thrmax);
    }
    __syncthreads();
  }
  drain_queue(buf, qbase, cnt, td, thrmax);
#pragma unroll
  for (int k = 0; k < NN; ++k) buf[qbase + k] = td[k];
  __syncthreads();

  if (wave == 0) {
    float sd[NN];
#pragma unroll
    for (int k = 0; k < NN; ++k) sd[k] = BIGF;
    float smax = BIGF;
    for (int w = 0; w < DNW; ++w) {
      for (int c = 0; c < NN; ++c) {
        insert16(sd, smax, buf[(w * 64 + lane) * CSTRIDE + c]);
      }
    }
    float loss = 0.0f;
#pragma unroll
    for (int k = 0; k < NN; ++k) {
      if (sd[k] < RAD2) loss += 1.0f / sqrtf(sd[k] + EPSF);
    }
    for (int off = 32; off > 0; off >>= 1) loss += __shfl_down(loss, off);
    if (lane == 0) block_sums[bid] = loss;
  }
}

// ============ launch ============

extern "C" void kernel_launch(void* const* d_in, const int* in_sizes, int n_in,
                              void* d_out, int out_size, void* d_ws, size_t ws_size,
                              hipStream_t stream) {
  const float* pts = (const float*)d_in[0];
  float* out = (float*)d_out;
  char* ws = (char*)d_ws;

  if (ws_size >= (size_t)WS_NEEDED) {
    int* counts = (int*)(ws + WS_COUNTS);
    int2* rngs = (int2*)(ws + WS_RANGES);
    int* cursor = (int*)(ws + WS_CURSOR);
    float4* sorted = (float4*)(ws + WS_SORTED);
    float* bsums = (float*)(ws + WS_BSUMS);

    hipMemsetAsync(counts, 0, NCELL_TOT * 4, stream);
    hist_kernel<<<(NTOT + 255) / 256, 256, 0, stream>>>(pts, counts);
    scan_kernel<<<NBATCH, 1024, 0, stream>>>(counts, rngs, cursor);
    scatter_kernel<<<(NTOT + 255) / 256, 256, 0, stream>>>(pts, cursor, sorted);
    search_kernel<<<SNB, STHR, 0, stream>>>(sorted, rngs, bsums);
    finalize_kernel<<<1, 256, 0, stream>>>(bsums, SNB, out);
  } else {
    float* bsums = (float*)ws;
    dense_kernel<<<DNB, DNT, 0, stream>>>(pts, bsums);
    finalize_kernel<<<1, 256, 0, stream>>>(bsums, DNB, out);
  }
}